// Round 1
// baseline (2044.092 us; speedup 1.0000x reference)
//
#include <hip/hip_runtime.h>
#include <math.h>

// ---------------------------------------------------------------------------
// GAT pipeline: 3x (GEMM+alpha fused -> CSR segment-softmax aggregate) + FC
// R8: GEMM inner loop fully unrolled (SSA kills the xv=xn v_movs of the
//     partial unroll), bounds check hoisted to group level (no per-load
//     cndmask), RB 4->5 so 10000 groups / 5120 waves = 1.95 (imbalance
//     2.5% instead of 23% at 2.44->3), launch_bounds(256,5) to keep the
//     5 blocks/CU LDS-capped occupancy. x loads stay per-lane broadcast
//     VMEM (R6 showed the scalar path serializes on SMEM).
// ---------------------------------------------------------------------------

// pass 1: cnt[dst]++ (atomic), remember each edge's arrival rank.
__global__ void count_rank_kernel(const int* __restrict__ ei, int E, int N,
                                  int* __restrict__ cnt, int* __restrict__ rank) {
    const int Etot = E + N;
    const int T = gridDim.x * blockDim.x;
    int e = blockIdx.x * blockDim.x + threadIdx.x;
#pragma unroll 4
    for (int u = 0; u < 4; ++u, e += T) {
        if (e < Etot) {
            int dst = (e < E) ? ei[E + e] : (e - E);   // self-loops appended
            rank[e] = atomicAdd(&cnt[dst], 1);
        }
    }
}

__global__ __launch_bounds__(1024) void scan_kernel(const int* __restrict__ cnt,
                                                    int N, int Etot,
                                                    int* __restrict__ row_ptr) {
    __shared__ int sums[1024];
    int tid = threadIdx.x;
    int chunk = (N + 1023) >> 10;
    int lo = tid * chunk;
    int hi = lo + chunk; if (hi > N) hi = N; if (lo > N) lo = N;
    int s = 0;
    for (int i = lo; i < hi; ++i) s += cnt[i];
    sums[tid] = s;
    __syncthreads();
    for (int off = 1; off < 1024; off <<= 1) {
        int t = (tid >= off) ? sums[tid - off] : 0;
        __syncthreads();
        sums[tid] += t;
        __syncthreads();
    }
    int run = sums[tid] - s;   // exclusive base for this thread's chunk
    for (int i = lo; i < hi; ++i) {
        row_ptr[i] = run;
        run += cnt[i];
    }
    if (tid == 0) row_ptr[N] = Etot;
}

// pass 3: pos = row_ptr[dst] + rank[e]; atomic-free scattered store.
__global__ void scatter_kernel(const int* __restrict__ ei, int E, int N,
                               const int* __restrict__ row_ptr,
                               const int* __restrict__ rank,
                               int* __restrict__ csr_src) {
    const int Etot = E + N;
    const int T = gridDim.x * blockDim.x;
    int e = blockIdx.x * blockDim.x + threadIdx.x;
#pragma unroll 4
    for (int u = 0; u < 4; ++u, e += T) {
        if (e < Etot) {
            int src, dst;
            if (e < E) { src = ei[e]; dst = ei[E + e]; }
            else       { src = e - E; dst = e - E; }
            csr_src[row_ptr[dst] + rank[e]] = src;
        }
    }
}

// ---------------------------------------------------------------------------
// GEMM: out[n, cb+m] = sum_k in[n,k]*W[k,cb+m].  256-thread blocks (4 waves),
// W chunk staged to LDS once (b128 conflict-free), grid-stride over row
// groups of RB=5 rows/wave. x loads are per-lane VMEM reads of a wave-uniform
// address (HW broadcast, one 16B fetch). k4 loop fully unrolled: single base
// VGPR pair + immediate offsets for all x loads, no register copies, no
// per-load bounds selects (bounds hoisted to group level).
// ALPHA: fused alpha_s/alpha_d via wave shfl reduction over the output row:
//   0=none  1=(H2,C32,PL1: segmented 32-lane)  2=(H2,C64,PL2)  3=(H1,C64,PL1)
// K*CHUNK <= 8192 (32 KB LDS).
// ---------------------------------------------------------------------------
template <int K, int CHUNK, int RB, int ALPHA>
__global__ __launch_bounds__(256, 5) void gemm_kernel(
        const float* __restrict__ in,
        const float* __restrict__ W,
        const float* __restrict__ bias,
        float* __restrict__ out,
        const float* __restrict__ a_src,
        const float* __restrict__ a_dst,
        float* __restrict__ alpS,
        float* __restrict__ alpD,
        int N, int M, int relu) {
    constexpr int PL = CHUNK / 64;
    constexpr int K4 = K / 4;
    __shared__ float wlds[K * CHUNK];
    const int cb = blockIdx.y * CHUNK;
    for (int idx = threadIdx.x; idx < K4 * CHUNK; idx += 256) {
        int k4 = idx / CHUNK, c = idx % CHUNK;
        const float* wp = W + (size_t)(4 * k4) * M + cb + c;
        float4 v;
        v.x = wp[0];
        v.y = wp[(size_t)M];
        v.z = wp[(size_t)2 * M];
        v.w = wp[(size_t)3 * M];
        ((float4*)wlds)[idx] = v;
    }
    __syncthreads();

    const int wid  = threadIdx.x >> 6;
    const int lane = threadIdx.x & 63;
    const float4* wlds4 = (const float4*)wlds;

    float b[PL], aSv[PL], aDv[PL];
#pragma unroll
    for (int j = 0; j < PL; ++j) {
        b[j] = bias ? bias[cb + lane + 64 * j] : 0.0f;
        if (ALPHA) { aSv[j] = a_src[lane + 64 * j]; aDv[j] = a_dst[lane + 64 * j]; }
    }

    const int groups = (N + RB - 1) / RB;
    for (int g = blockIdx.x * 4 + wid; g < groups; g += gridDim.x * 4) {
        const int n0 = g * RB;
        const bool full = (n0 + RB <= N);

        float acc[RB][PL];
#pragma unroll
        for (int r = 0; r < RB; ++r)
#pragma unroll
            for (int j = 0; j < PL; ++j) acc[r][j] = 0.0f;

        const float4* xp = (const float4*)(in + (size_t)n0 * K);

        if (full) {
            // ---- fast path: no bounds checks, fully unrolled straight line.
            float4 xv[RB], xn[RB];
#pragma unroll
            for (int r = 0; r < RB; ++r) xv[r] = xp[r * K4];
#pragma unroll
            for (int k4 = 0; k4 < K4; ++k4) {
                if (k4 + 1 < K4) {
#pragma unroll
                    for (int r = 0; r < RB; ++r)
                        xn[r] = xp[r * K4 + k4 + 1];
                }
#pragma unroll
                for (int j = 0; j < PL; ++j) {
                    float4 wv = wlds4[k4 * CHUNK + lane + 64 * j];
#pragma unroll
                    for (int r = 0; r < RB; ++r) {
                        acc[r][j] += xv[r].x * wv.x;
                        acc[r][j] += xv[r].y * wv.y;
                        acc[r][j] += xv[r].z * wv.z;
                        acc[r][j] += xv[r].w * wv.w;
                    }
                }
                if (k4 + 1 < K4) {
#pragma unroll
                    for (int r = 0; r < RB; ++r) xv[r] = xn[r];
                }
            }
        } else {
            // ---- tail path (never taken when N % RB == 0): simple, guarded.
#pragma unroll 1
            for (int k4 = 0; k4 < K4; ++k4) {
#pragma unroll 1
                for (int r = 0; r < RB; ++r) {
                    if (n0 + r >= N) break;
                    float4 xr = xp[(size_t)r * K4 + k4];
#pragma unroll
                    for (int j = 0; j < PL; ++j) {
                        float4 wv = wlds4[k4 * CHUNK + lane + 64 * j];
                        acc[r][j] += xr.x * wv.x;
                        acc[r][j] += xr.y * wv.y;
                        acc[r][j] += xr.z * wv.z;
                        acc[r][j] += xr.w * wv.w;
                    }
                }
            }
        }

#pragma unroll
        for (int r = 0; r < RB; ++r) {
            if (!full && n0 + r >= N) break;
            const int n = n0 + r;
            float v[PL];
#pragma unroll
            for (int j = 0; j < PL; ++j) {
                v[j] = acc[r][j] + b[j];
                if (relu) v[j] = fmaxf(v[j], 0.0f);
                out[(size_t)n * M + cb + lane + 64 * j] = v[j];
            }
            if (ALPHA) {
                float ps[PL], pd[PL];
#pragma unroll
                for (int j = 0; j < PL; ++j) { ps[j] = v[j] * aSv[j]; pd[j] = v[j] * aDv[j]; }
                const int m0 = (ALPHA == 1) ? 16 : 32;   // 32-lane segmented vs full wave
                for (int m = m0; m >= 1; m >>= 1) {
#pragma unroll
                    for (int j = 0; j < PL; ++j) {
                        ps[j] += __shfl_xor(ps[j], m, 64);
                        pd[j] += __shfl_xor(pd[j], m, 64);
                    }
                }
                if (ALPHA == 1) {
                    if ((lane & 31) == 0) {
                        int idx = n * 2 + (lane >> 5);
                        alpS[idx] = ps[0]; alpD[idx] = pd[0];
                    }
                } else if (ALPHA == 2) {
                    if (lane == 0) {
#pragma unroll
                        for (int j = 0; j < PL; ++j) {
                            alpS[n * 2 + j] = ps[j]; alpD[n * 2 + j] = pd[j];
                        }
                    }
                } else {
                    if (lane == 0) { alpS[n] = ps[0]; alpD[n] = pd[0]; }
                }
            }
        }
    }
}

// ---------------------------------------------------------------------------
// Aggregate: one wave per dst node, single pass, online softmax, 8-edge unroll.
// PL==1: lane -> (head=lane/C, c=lane%C)  [needs H*C==64]
// PL==2: lane covers (head=j, c=lane), j=0,1 [needs C==64,H==2]
// ---------------------------------------------------------------------------
template <int H, int C, int PL>
__global__ __launch_bounds__(256) void aggregate_kernel(
        const float* __restrict__ h,
        const float* __restrict__ alpha_s,
        const float* __restrict__ alpha_d,
        const int* __restrict__ row_ptr,
        const int* __restrict__ csr_src,
        const float* __restrict__ bias,
        float* __restrict__ out, int N) {
    constexpr int M = H * C;
    constexpr int U = 8;
    const int wid  = threadIdx.x >> 6;
    const int lane = threadIdx.x & 63;
    const int n = blockIdx.x * 4 + wid;
    if (n >= N) return;

    const int lo = row_ptr[n], hi = row_ptr[n + 1];

    int head[PL], col[PL];
    float adv[PL], mx[PL], den[PL], acc[PL];
#pragma unroll
    for (int j = 0; j < PL; ++j) {
        head[j] = (PL == 1) ? (lane / C) : j;
        col[j]  = (PL == 1) ? lane : (j * C + lane);
        adv[j]  = alpha_d[n * H + head[j]];
        mx[j]   = -INFINITY;
        den[j]  = 0.0f;
        acc[j]  = 0.0f;
    }

    int e = lo;
    for (; e + U <= hi; e += U) {
        int s[U];
#pragma unroll
        for (int u = 0; u < U; ++u) s[u] = csr_src[e + u];
        float ev[U][PL], hv[U][PL];
#pragma unroll
        for (int u = 0; u < U; ++u)
#pragma unroll
            for (int j = 0; j < PL; ++j)
                ev[u][j] = alpha_s[s[u] * H + head[j]];
#pragma unroll
        for (int u = 0; u < U; ++u)
#pragma unroll
            for (int j = 0; j < PL; ++j)
                hv[u][j] = h[(size_t)s[u] * M + col[j]];
#pragma unroll
        for (int u = 0; u < U; ++u)
#pragma unroll
            for (int j = 0; j < PL; ++j) {
                float evv = ev[u][j] + adv[j];
                evv = evv > 0.0f ? evv : 0.2f * evv;
                float mnew = fmaxf(mx[j], evv);
                float sc = __expf(mx[j] - mnew);   // first edge: exp(-inf)=0
                float p  = __expf(evv - mnew);
                den[j] = den[j] * sc + p;
                acc[j] = acc[j] * sc + p * hv[u][j];
                mx[j]  = mnew;
            }
    }
    for (; e < hi; ++e) {
        int s = csr_src[e];
#pragma unroll
        for (int j = 0; j < PL; ++j) {
            float evv = alpha_s[s * H + head[j]] + adv[j];
            evv = evv > 0.0f ? evv : 0.2f * evv;
            float mnew = fmaxf(mx[j], evv);
            float sc = __expf(mx[j] - mnew);
            float p  = __expf(evv - mnew);
            den[j] = den[j] * sc + p;
            acc[j] = acc[j] * sc + p * h[(size_t)s * M + col[j]];
            mx[j]  = mnew;
        }
    }

#pragma unroll
    for (int j = 0; j < PL; ++j) {
        float v = acc[j] / den[j] + bias[col[j]];
        out[(size_t)n * M + col[j]] = fmaxf(v, 0.0f);
    }
}

// ---------------------------------------------------------------------------

extern "C" void kernel_launch(void* const* d_in, const int* in_sizes, int n_in,
                              void* d_out, int out_size, void* d_ws, size_t ws_size,
                              hipStream_t stream) {
    const float* x   = (const float*)d_in[0];
    const int*   ei  = (const int*)  d_in[1];
    const float* w1  = (const float*)d_in[2];
    const float* as1 = (const float*)d_in[3];
    const float* ad1 = (const float*)d_in[4];
    const float* b1  = (const float*)d_in[5];
    const float* w2  = (const float*)d_in[6];
    const float* as2 = (const float*)d_in[7];
    const float* ad2 = (const float*)d_in[8];
    const float* b2  = (const float*)d_in[9];
    const float* w3  = (const float*)d_in[10];
    const float* as3 = (const float*)d_in[11];
    const float* ad3 = (const float*)d_in[12];
    const float* b3  = (const float*)d_in[13];
    const float* fcw = (const float*)d_in[14];
    const float* fcb = (const float*)d_in[15];
    float* out = (float*)d_out;

    const int N = in_sizes[0] / 128;
    const int E = in_sizes[1] / 2;
    const int Etot = E + N;

    // workspace carve-up (256B aligned regions)
    char* p = (char*)d_ws;
    auto alloc = [&](size_t bytes) {
        char* r = p;
        p += (bytes + 255) & ~(size_t)255;
        return r;
    };
    int*   cnt     = (int*)  alloc((size_t)N * 4);
    int*   row_ptr = (int*)  alloc((size_t)(N + 1) * 4);
    int*   rank    = (int*)  alloc((size_t)Etot * 4);
    int*   csr_src = (int*)  alloc((size_t)Etot * 4);
    float* bufA    = (float*)alloc((size_t)N * 128 * 4);
    float* bufB    = (float*)alloc((size_t)N * 128 * 4);
    float* alpS    = (float*)alloc((size_t)N * 2 * 4);
    float* alpD    = (float*)alloc((size_t)N * 2 * 4);
    (void)ws_size; (void)n_in; (void)out_size;

    // ---- build CSR by dst (atomics only in pass 1) ----
    hipMemsetAsync(cnt, 0, (size_t)N * 4, stream);
    int eb4 = (Etot / 4 + 255) / 256 + 1;   // 4 edges/thread
    count_rank_kernel<<<eb4, 256, 0, stream>>>(ei, E, N, cnt, rank);
    scan_kernel<<<1, 1024, 0, stream>>>(cnt, N, Etot, row_ptr);
    scatter_kernel<<<eb4, 256, 0, stream>>>(ei, E, N, row_ptr, rank, csr_src);

    int gb = (N + 3) / 4;         // aggregate: 4 waves/block, 1 node/wave
    const int GB = 1280;          // gemm persistent blocks: 5/CU (LDS cap)

    // ---- layer 1: 128 -> H2 x C32, concat ----
    gemm_kernel<128, 64, 5, 1><<<dim3(GB, 1), 256, 0, stream>>>(
        x, w1, nullptr, bufA, as1, ad1, alpS, alpD, N, 64, 0);
    aggregate_kernel<2, 32, 1><<<gb, 256, 0, stream>>>(bufA, alpS, alpD, row_ptr, csr_src, b1, bufB, N);

    // ---- layer 2: 64 -> H2 x C64, concat ----
    gemm_kernel<64, 128, 5, 2><<<dim3(GB, 1), 256, 0, stream>>>(
        bufB, w2, nullptr, bufA, as2, ad2, alpS, alpD, N, 128, 0);
    aggregate_kernel<2, 64, 2><<<gb, 256, 0, stream>>>(bufA, alpS, alpD, row_ptr, csr_src, b2, bufB, N);

    // ---- layer 3: 128 -> H1 x C64, mean (=identity for 1 head) ----
    gemm_kernel<128, 64, 5, 3><<<dim3(GB, 1), 256, 0, stream>>>(
        bufB, w3, nullptr, bufA, as3, ad3, alpS, alpD, N, 64, 0);
    aggregate_kernel<1, 64, 1><<<gb, 256, 0, stream>>>(bufA, alpS, alpD, row_ptr, csr_src, b3, bufB, N);

    // ---- FC: 64 -> 512 + relu ----
    gemm_kernel<64, 128, 5, 0><<<dim3(GB / 4, 4), 256, 0, stream>>>(
        bufB, fcw, fcb, out, nullptr, nullptr, nullptr, nullptr, N, 512, 1);
}

// Round 2
// 887.614 us; speedup vs baseline: 2.3029x; 2.3029x over previous
//
#include <hip/hip_runtime.h>
#include <math.h>

// ---------------------------------------------------------------------------
// GAT pipeline: 3x (GEMM+alpha fused -> CSR segment-softmax aggregate) + FC
// R9: revert R8's full-unroll + launch_bounds(256,5) (caused massive scratch
//     spill: 3 GB HBM traffic, VALUBusy 6%). Back to R7's partial-unroll
//     ping-pong loop, but RB 4->8: doubles per-iter FMA issue (128 cyc) so
//     the distance-1 x prefetch covers L2 latency, and halves LDS-pipe
//     demand per FMA (2 ds_read_b128 now feed 64 FMA). N%8==0 so the
//     guarded tail never runs. Grid 1024 = 4 blocks/CU (VGPR ~120, LDS 32K).
// ---------------------------------------------------------------------------

// pass 1: cnt[dst]++ (atomic), remember each edge's arrival rank.
__global__ void count_rank_kernel(const int* __restrict__ ei, int E, int N,
                                  int* __restrict__ cnt, int* __restrict__ rank) {
    const int Etot = E + N;
    const int T = gridDim.x * blockDim.x;
    int e = blockIdx.x * blockDim.x + threadIdx.x;
#pragma unroll 4
    for (int u = 0; u < 4; ++u, e += T) {
        if (e < Etot) {
            int dst = (e < E) ? ei[E + e] : (e - E);   // self-loops appended
            rank[e] = atomicAdd(&cnt[dst], 1);
        }
    }
}

__global__ __launch_bounds__(1024) void scan_kernel(const int* __restrict__ cnt,
                                                    int N, int Etot,
                                                    int* __restrict__ row_ptr) {
    __shared__ int sums[1024];
    int tid = threadIdx.x;
    int chunk = (N + 1023) >> 10;
    int lo = tid * chunk;
    int hi = lo + chunk; if (hi > N) hi = N; if (lo > N) lo = N;
    int s = 0;
    for (int i = lo; i < hi; ++i) s += cnt[i];
    sums[tid] = s;
    __syncthreads();
    for (int off = 1; off < 1024; off <<= 1) {
        int t = (tid >= off) ? sums[tid - off] : 0;
        __syncthreads();
        sums[tid] += t;
        __syncthreads();
    }
    int run = sums[tid] - s;   // exclusive base for this thread's chunk
    for (int i = lo; i < hi; ++i) {
        row_ptr[i] = run;
        run += cnt[i];
    }
    if (tid == 0) row_ptr[N] = Etot;
}

// pass 3: pos = row_ptr[dst] + rank[e]; atomic-free scattered store.
__global__ void scatter_kernel(const int* __restrict__ ei, int E, int N,
                               const int* __restrict__ row_ptr,
                               const int* __restrict__ rank,
                               int* __restrict__ csr_src) {
    const int Etot = E + N;
    const int T = gridDim.x * blockDim.x;
    int e = blockIdx.x * blockDim.x + threadIdx.x;
#pragma unroll 4
    for (int u = 0; u < 4; ++u, e += T) {
        if (e < Etot) {
            int src, dst;
            if (e < E) { src = ei[e]; dst = ei[E + e]; }
            else       { src = e - E; dst = e - E; }
            csr_src[row_ptr[dst] + rank[e]] = src;
        }
    }
}

// ---------------------------------------------------------------------------
// GEMM: out[n, cb+m] = sum_k in[n,k]*W[k,cb+m].  256-thread blocks (4 waves),
// W chunk staged to LDS once (b128 conflict-free), grid-stride over row
// groups of RB=8 rows/wave. x loads are per-lane VMEM reads of a wave-uniform
// address (HW broadcast, one 16B fetch) with distance-1 explicit prefetch;
// at RB=8 one iter issues 128 cycles of FMA, covering L2 load latency.
// ALPHA: fused alpha_s/alpha_d via wave shfl reduction over the output row:
//   0=none  1=(H2,C32,PL1: segmented 32-lane)  2=(H2,C64,PL2)  3=(H1,C64,PL1)
// K*CHUNK <= 8192 (32 KB LDS).
// ---------------------------------------------------------------------------
template <int K, int CHUNK, int RB, int ALPHA>
__global__ __launch_bounds__(256) void gemm_kernel(
        const float* __restrict__ in,
        const float* __restrict__ W,
        const float* __restrict__ bias,
        float* __restrict__ out,
        const float* __restrict__ a_src,
        const float* __restrict__ a_dst,
        float* __restrict__ alpS,
        float* __restrict__ alpD,
        int N, int M, int relu) {
    constexpr int PL = CHUNK / 64;
    constexpr int K4 = K / 4;
    __shared__ float wlds[K * CHUNK];
    const int cb = blockIdx.y * CHUNK;
    for (int idx = threadIdx.x; idx < K4 * CHUNK; idx += 256) {
        int k4 = idx / CHUNK, c = idx % CHUNK;
        const float* wp = W + (size_t)(4 * k4) * M + cb + c;
        float4 v;
        v.x = wp[0];
        v.y = wp[(size_t)M];
        v.z = wp[(size_t)2 * M];
        v.w = wp[(size_t)3 * M];
        ((float4*)wlds)[idx] = v;
    }
    __syncthreads();

    const int wid  = threadIdx.x >> 6;
    const int lane = threadIdx.x & 63;
    const float4* wlds4 = (const float4*)wlds;

    float b[PL], aSv[PL], aDv[PL];
#pragma unroll
    for (int j = 0; j < PL; ++j) {
        b[j] = bias ? bias[cb + lane + 64 * j] : 0.0f;
        if (ALPHA) { aSv[j] = a_src[lane + 64 * j]; aDv[j] = a_dst[lane + 64 * j]; }
    }

    const int groups = (N + RB - 1) / RB;
    for (int g = blockIdx.x * 4 + wid; g < groups; g += gridDim.x * 4) {
        const int n0 = g * RB;
        const bool full = (n0 + RB <= N);

        float acc[RB][PL];
#pragma unroll
        for (int r = 0; r < RB; ++r)
#pragma unroll
            for (int j = 0; j < PL; ++j) acc[r][j] = 0.0f;

        const float4* xp = (const float4*)(in + (size_t)n0 * K);

        if (full) {
            // ---- fast path: R7-style ping-pong, distance-1 prefetch,
            //      partial unroll only (full unroll spilled in R8).
            float4 xv[RB], xn[RB];
#pragma unroll
            for (int r = 0; r < RB; ++r) xv[r] = xp[r * K4];
#pragma unroll 2
            for (int k4 = 0; k4 < K4; ++k4) {
                if (k4 + 1 < K4) {
#pragma unroll
                    for (int r = 0; r < RB; ++r)
                        xn[r] = xp[r * K4 + k4 + 1];
                }
#pragma unroll
                for (int j = 0; j < PL; ++j) {
                    float4 wv = wlds4[k4 * CHUNK + lane + 64 * j];
#pragma unroll
                    for (int r = 0; r < RB; ++r) {
                        acc[r][j] += xv[r].x * wv.x;
                        acc[r][j] += xv[r].y * wv.y;
                        acc[r][j] += xv[r].z * wv.z;
                        acc[r][j] += xv[r].w * wv.w;
                    }
                }
                if (k4 + 1 < K4) {
#pragma unroll
                    for (int r = 0; r < RB; ++r) xv[r] = xn[r];
                }
            }
        } else {
            // ---- tail path (never taken when N % RB == 0): simple, guarded.
#pragma unroll 1
            for (int k4 = 0; k4 < K4; ++k4) {
#pragma unroll 1
                for (int r = 0; r < RB; ++r) {
                    if (n0 + r >= N) break;
                    float4 xr = xp[(size_t)r * K4 + k4];
#pragma unroll
                    for (int j = 0; j < PL; ++j) {
                        float4 wv = wlds4[k4 * CHUNK + lane + 64 * j];
                        acc[r][j] += xr.x * wv.x;
                        acc[r][j] += xr.y * wv.y;
                        acc[r][j] += xr.z * wv.z;
                        acc[r][j] += xr.w * wv.w;
                    }
                }
            }
        }

#pragma unroll
        for (int r = 0; r < RB; ++r) {
            if (!full && n0 + r >= N) break;
            const int n = n0 + r;
            float v[PL];
#pragma unroll
            for (int j = 0; j < PL; ++j) {
                v[j] = acc[r][j] + b[j];
                if (relu) v[j] = fmaxf(v[j], 0.0f);
                out[(size_t)n * M + cb + lane + 64 * j] = v[j];
            }
            if (ALPHA) {
                float ps[PL], pd[PL];
#pragma unroll
                for (int j = 0; j < PL; ++j) { ps[j] = v[j] * aSv[j]; pd[j] = v[j] * aDv[j]; }
                const int m0 = (ALPHA == 1) ? 16 : 32;   // 32-lane segmented vs full wave
                for (int m = m0; m >= 1; m >>= 1) {
#pragma unroll
                    for (int j = 0; j < PL; ++j) {
                        ps[j] += __shfl_xor(ps[j], m, 64);
                        pd[j] += __shfl_xor(pd[j], m, 64);
                    }
                }
                if (ALPHA == 1) {
                    if ((lane & 31) == 0) {
                        int idx = n * 2 + (lane >> 5);
                        alpS[idx] = ps[0]; alpD[idx] = pd[0];
                    }
                } else if (ALPHA == 2) {
                    if (lane == 0) {
#pragma unroll
                        for (int j = 0; j < PL; ++j) {
                            alpS[n * 2 + j] = ps[j]; alpD[n * 2 + j] = pd[j];
                        }
                    }
                } else {
                    if (lane == 0) { alpS[n] = ps[0]; alpD[n] = pd[0]; }
                }
            }
        }
    }
}

// ---------------------------------------------------------------------------
// Aggregate: one wave per dst node, single pass, online softmax, 8-edge unroll.
// PL==1: lane -> (head=lane/C, c=lane%C)  [needs H*C==64]
// PL==2: lane covers (head=j, c=lane), j=0,1 [needs C==64,H==2]
// ---------------------------------------------------------------------------
template <int H, int C, int PL>
__global__ __launch_bounds__(256) void aggregate_kernel(
        const float* __restrict__ h,
        const float* __restrict__ alpha_s,
        const float* __restrict__ alpha_d,
        const int* __restrict__ row_ptr,
        const int* __restrict__ csr_src,
        const float* __restrict__ bias,
        float* __restrict__ out, int N) {
    constexpr int M = H * C;
    constexpr int U = 8;
    const int wid  = threadIdx.x >> 6;
    const int lane = threadIdx.x & 63;
    const int n = blockIdx.x * 4 + wid;
    if (n >= N) return;

    const int lo = row_ptr[n], hi = row_ptr[n + 1];

    int head[PL], col[PL];
    float adv[PL], mx[PL], den[PL], acc[PL];
#pragma unroll
    for (int j = 0; j < PL; ++j) {
        head[j] = (PL == 1) ? (lane / C) : j;
        col[j]  = (PL == 1) ? lane : (j * C + lane);
        adv[j]  = alpha_d[n * H + head[j]];
        mx[j]   = -INFINITY;
        den[j]  = 0.0f;
        acc[j]  = 0.0f;
    }

    int e = lo;
    for (; e + U <= hi; e += U) {
        int s[U];
#pragma unroll
        for (int u = 0; u < U; ++u) s[u] = csr_src[e + u];
        float ev[U][PL], hv[U][PL];
#pragma unroll
        for (int u = 0; u < U; ++u)
#pragma unroll
            for (int j = 0; j < PL; ++j)
                ev[u][j] = alpha_s[s[u] * H + head[j]];
#pragma unroll
        for (int u = 0; u < U; ++u)
#pragma unroll
            for (int j = 0; j < PL; ++j)
                hv[u][j] = h[(size_t)s[u] * M + col[j]];
#pragma unroll
        for (int u = 0; u < U; ++u)
#pragma unroll
            for (int j = 0; j < PL; ++j) {
                float evv = ev[u][j] + adv[j];
                evv = evv > 0.0f ? evv : 0.2f * evv;
                float mnew = fmaxf(mx[j], evv);
                float sc = __expf(mx[j] - mnew);   // first edge: exp(-inf)=0
                float p  = __expf(evv - mnew);
                den[j] = den[j] * sc + p;
                acc[j] = acc[j] * sc + p * hv[u][j];
                mx[j]  = mnew;
            }
    }
    for (; e < hi; ++e) {
        int s = csr_src[e];
#pragma unroll
        for (int j = 0; j < PL; ++j) {
            float evv = alpha_s[s * H + head[j]] + adv[j];
            evv = evv > 0.0f ? evv : 0.2f * evv;
            float mnew = fmaxf(mx[j], evv);
            float sc = __expf(mx[j] - mnew);
            float p  = __expf(evv - mnew);
            den[j] = den[j] * sc + p;
            acc[j] = acc[j] * sc + p * h[(size_t)s * M + col[j]];
            mx[j]  = mnew;
        }
    }

#pragma unroll
    for (int j = 0; j < PL; ++j) {
        float v = acc[j] / den[j] + bias[col[j]];
        out[(size_t)n * M + col[j]] = fmaxf(v, 0.0f);
    }
}

// ---------------------------------------------------------------------------

extern "C" void kernel_launch(void* const* d_in, const int* in_sizes, int n_in,
                              void* d_out, int out_size, void* d_ws, size_t ws_size,
                              hipStream_t stream) {
    const float* x   = (const float*)d_in[0];
    const int*   ei  = (const int*)  d_in[1];
    const float* w1  = (const float*)d_in[2];
    const float* as1 = (const float*)d_in[3];
    const float* ad1 = (const float*)d_in[4];
    const float* b1  = (const float*)d_in[5];
    const float* w2  = (const float*)d_in[6];
    const float* as2 = (const float*)d_in[7];
    const float* ad2 = (const float*)d_in[8];
    const float* b2  = (const float*)d_in[9];
    const float* w3  = (const float*)d_in[10];
    const float* as3 = (const float*)d_in[11];
    const float* ad3 = (const float*)d_in[12];
    const float* b3  = (const float*)d_in[13];
    const float* fcw = (const float*)d_in[14];
    const float* fcb = (const float*)d_in[15];
    float* out = (float*)d_out;

    const int N = in_sizes[0] / 128;
    const int E = in_sizes[1] / 2;
    const int Etot = E + N;

    // workspace carve-up (256B aligned regions)
    char* p = (char*)d_ws;
    auto alloc = [&](size_t bytes) {
        char* r = p;
        p += (bytes + 255) & ~(size_t)255;
        return r;
    };
    int*   cnt     = (int*)  alloc((size_t)N * 4);
    int*   row_ptr = (int*)  alloc((size_t)(N + 1) * 4);
    int*   rank    = (int*)  alloc((size_t)Etot * 4);
    int*   csr_src = (int*)  alloc((size_t)Etot * 4);
    float* bufA    = (float*)alloc((size_t)N * 128 * 4);
    float* bufB    = (float*)alloc((size_t)N * 128 * 4);
    float* alpS    = (float*)alloc((size_t)N * 2 * 4);
    float* alpD    = (float*)alloc((size_t)N * 2 * 4);
    (void)ws_size; (void)n_in; (void)out_size;

    // ---- build CSR by dst (atomics only in pass 1) ----
    hipMemsetAsync(cnt, 0, (size_t)N * 4, stream);
    int eb4 = (Etot / 4 + 255) / 256 + 1;   // 4 edges/thread
    count_rank_kernel<<<eb4, 256, 0, stream>>>(ei, E, N, cnt, rank);
    scan_kernel<<<1, 1024, 0, stream>>>(cnt, N, Etot, row_ptr);
    scatter_kernel<<<eb4, 256, 0, stream>>>(ei, E, N, row_ptr, rank, csr_src);

    int gb = (N + 3) / 4;         // aggregate: 4 waves/block, 1 node/wave
    const int GB = 1024;          // gemm persistent blocks: 4/CU (VGPR/LDS cap at RB=8)

    // ---- layer 1: 128 -> H2 x C32, concat ----
    gemm_kernel<128, 64, 8, 1><<<dim3(GB, 1), 256, 0, stream>>>(
        x, w1, nullptr, bufA, as1, ad1, alpS, alpD, N, 64, 0);
    aggregate_kernel<2, 32, 1><<<gb, 256, 0, stream>>>(bufA, alpS, alpD, row_ptr, csr_src, b1, bufB, N);

    // ---- layer 2: 64 -> H2 x C64, concat ----
    gemm_kernel<64, 128, 8, 2><<<dim3(GB, 1), 256, 0, stream>>>(
        bufB, w2, nullptr, bufA, as2, ad2, alpS, alpD, N, 128, 0);
    aggregate_kernel<2, 64, 2><<<gb, 256, 0, stream>>>(bufA, alpS, alpD, row_ptr, csr_src, b2, bufB, N);

    // ---- layer 3: 128 -> H1 x C64, mean (=identity for 1 head) ----
    gemm_kernel<128, 64, 8, 3><<<dim3(GB, 1), 256, 0, stream>>>(
        bufB, w3, nullptr, bufA, as3, ad3, alpS, alpD, N, 64, 0);
    aggregate_kernel<1, 64, 1><<<gb, 256, 0, stream>>>(bufA, alpS, alpD, row_ptr, csr_src, b3, bufB, N);

    // ---- FC: 64 -> 512 + relu ----
    gemm_kernel<64, 128, 8, 0><<<dim3(GB / 4, 4), 256, 0, stream>>>(
        bufB, fcw, fcb, out, nullptr, nullptr, nullptr, nullptr, N, 512, 1);
}

// Round 3
// 849.992 us; speedup vs baseline: 2.4048x; 1.0443x over previous
//
#include <hip/hip_runtime.h>
#include <math.h>

// ---------------------------------------------------------------------------
// GAT pipeline: 3x (GEMM+alpha fused -> CSR segment-softmax aggregate) + FC
// R10: aggregate rewritten. R9 counters: agg VALUBusy 92% -- the online
//      softmax chain (leaky/fmax/2x expf/rescale) was replicated across all
//      64 lanes per edge (logit depends only on edge+head). Now: phase A
//      computes logits LANE-PARALLEL over 64-edge chunks (coalesced csr_src,
//      float2 alpha_s, 1 exp per 64 edges), rescales m/den/acc once per
//      CHUNK, butterfly-reduces max/den; phase B broadcasts (src,p) via a
//      per-wave LDS slice and does only loads+FMA per edge (~8 slots vs ~30).
//      GEMM (RB=8 ping-pong) and CSR build unchanged from R9.
// ---------------------------------------------------------------------------

// pass 1: cnt[dst]++ (atomic), remember each edge's arrival rank.
__global__ void count_rank_kernel(const int* __restrict__ ei, int E, int N,
                                  int* __restrict__ cnt, int* __restrict__ rank) {
    const int Etot = E + N;
    const int T = gridDim.x * blockDim.x;
    int e = blockIdx.x * blockDim.x + threadIdx.x;
#pragma unroll 4
    for (int u = 0; u < 4; ++u, e += T) {
        if (e < Etot) {
            int dst = (e < E) ? ei[E + e] : (e - E);   // self-loops appended
            rank[e] = atomicAdd(&cnt[dst], 1);
        }
    }
}

__global__ __launch_bounds__(1024) void scan_kernel(const int* __restrict__ cnt,
                                                    int N, int Etot,
                                                    int* __restrict__ row_ptr) {
    __shared__ int sums[1024];
    int tid = threadIdx.x;
    int chunk = (N + 1023) >> 10;
    int lo = tid * chunk;
    int hi = lo + chunk; if (hi > N) hi = N; if (lo > N) lo = N;
    int s = 0;
    for (int i = lo; i < hi; ++i) s += cnt[i];
    sums[tid] = s;
    __syncthreads();
    for (int off = 1; off < 1024; off <<= 1) {
        int t = (tid >= off) ? sums[tid - off] : 0;
        __syncthreads();
        sums[tid] += t;
        __syncthreads();
    }
    int run = sums[tid] - s;   // exclusive base for this thread's chunk
    for (int i = lo; i < hi; ++i) {
        row_ptr[i] = run;
        run += cnt[i];
    }
    if (tid == 0) row_ptr[N] = Etot;
}

// pass 3: pos = row_ptr[dst] + rank[e]; atomic-free scattered store.
__global__ void scatter_kernel(const int* __restrict__ ei, int E, int N,
                               const int* __restrict__ row_ptr,
                               const int* __restrict__ rank,
                               int* __restrict__ csr_src) {
    const int Etot = E + N;
    const int T = gridDim.x * blockDim.x;
    int e = blockIdx.x * blockDim.x + threadIdx.x;
#pragma unroll 4
    for (int u = 0; u < 4; ++u, e += T) {
        if (e < Etot) {
            int src, dst;
            if (e < E) { src = ei[e]; dst = ei[E + e]; }
            else       { src = e - E; dst = e - E; }
            csr_src[row_ptr[dst] + rank[e]] = src;
        }
    }
}

// ---------------------------------------------------------------------------
// GEMM: out[n, cb+m] = sum_k in[n,k]*W[k,cb+m].  256-thread blocks (4 waves),
// W chunk staged to LDS once (b128 conflict-free), grid-stride over row
// groups of RB=8 rows/wave, distance-1 x prefetch (R9-validated).
// ALPHA: fused alpha_s/alpha_d via wave shfl reduction over the output row:
//   0=none  1=(H2,C32,PL1: segmented 32-lane)  2=(H2,C64,PL2)  3=(H1,C64,PL1)
// K*CHUNK <= 8192 (32 KB LDS).
// ---------------------------------------------------------------------------
template <int K, int CHUNK, int RB, int ALPHA>
__global__ __launch_bounds__(256) void gemm_kernel(
        const float* __restrict__ in,
        const float* __restrict__ W,
        const float* __restrict__ bias,
        float* __restrict__ out,
        const float* __restrict__ a_src,
        const float* __restrict__ a_dst,
        float* __restrict__ alpS,
        float* __restrict__ alpD,
        int N, int M, int relu) {
    constexpr int PL = CHUNK / 64;
    constexpr int K4 = K / 4;
    __shared__ float wlds[K * CHUNK];
    const int cb = blockIdx.y * CHUNK;
    for (int idx = threadIdx.x; idx < K4 * CHUNK; idx += 256) {
        int k4 = idx / CHUNK, c = idx % CHUNK;
        const float* wp = W + (size_t)(4 * k4) * M + cb + c;
        float4 v;
        v.x = wp[0];
        v.y = wp[(size_t)M];
        v.z = wp[(size_t)2 * M];
        v.w = wp[(size_t)3 * M];
        ((float4*)wlds)[idx] = v;
    }
    __syncthreads();

    const int wid  = threadIdx.x >> 6;
    const int lane = threadIdx.x & 63;
    const float4* wlds4 = (const float4*)wlds;

    float b[PL], aSv[PL], aDv[PL];
#pragma unroll
    for (int j = 0; j < PL; ++j) {
        b[j] = bias ? bias[cb + lane + 64 * j] : 0.0f;
        if (ALPHA) { aSv[j] = a_src[lane + 64 * j]; aDv[j] = a_dst[lane + 64 * j]; }
    }

    const int groups = (N + RB - 1) / RB;
    for (int g = blockIdx.x * 4 + wid; g < groups; g += gridDim.x * 4) {
        const int n0 = g * RB;
        const bool full = (n0 + RB <= N);

        float acc[RB][PL];
#pragma unroll
        for (int r = 0; r < RB; ++r)
#pragma unroll
            for (int j = 0; j < PL; ++j) acc[r][j] = 0.0f;

        const float4* xp = (const float4*)(in + (size_t)n0 * K);

        if (full) {
            float4 xv[RB], xn[RB];
#pragma unroll
            for (int r = 0; r < RB; ++r) xv[r] = xp[r * K4];
#pragma unroll 2
            for (int k4 = 0; k4 < K4; ++k4) {
                if (k4 + 1 < K4) {
#pragma unroll
                    for (int r = 0; r < RB; ++r)
                        xn[r] = xp[r * K4 + k4 + 1];
                }
#pragma unroll
                for (int j = 0; j < PL; ++j) {
                    float4 wv = wlds4[k4 * CHUNK + lane + 64 * j];
#pragma unroll
                    for (int r = 0; r < RB; ++r) {
                        acc[r][j] += xv[r].x * wv.x;
                        acc[r][j] += xv[r].y * wv.y;
                        acc[r][j] += xv[r].z * wv.z;
                        acc[r][j] += xv[r].w * wv.w;
                    }
                }
                if (k4 + 1 < K4) {
#pragma unroll
                    for (int r = 0; r < RB; ++r) xv[r] = xn[r];
                }
            }
        } else {
#pragma unroll 1
            for (int k4 = 0; k4 < K4; ++k4) {
#pragma unroll 1
                for (int r = 0; r < RB; ++r) {
                    if (n0 + r >= N) break;
                    float4 xr = xp[(size_t)r * K4 + k4];
#pragma unroll
                    for (int j = 0; j < PL; ++j) {
                        float4 wv = wlds4[k4 * CHUNK + lane + 64 * j];
                        acc[r][j] += xr.x * wv.x;
                        acc[r][j] += xr.y * wv.y;
                        acc[r][j] += xr.z * wv.z;
                        acc[r][j] += xr.w * wv.w;
                    }
                }
            }
        }

#pragma unroll
        for (int r = 0; r < RB; ++r) {
            if (!full && n0 + r >= N) break;
            const int n = n0 + r;
            float v[PL];
#pragma unroll
            for (int j = 0; j < PL; ++j) {
                v[j] = acc[r][j] + b[j];
                if (relu) v[j] = fmaxf(v[j], 0.0f);
                out[(size_t)n * M + cb + lane + 64 * j] = v[j];
            }
            if (ALPHA) {
                float ps[PL], pd[PL];
#pragma unroll
                for (int j = 0; j < PL; ++j) { ps[j] = v[j] * aSv[j]; pd[j] = v[j] * aDv[j]; }
                const int m0 = (ALPHA == 1) ? 16 : 32;
                for (int m = m0; m >= 1; m >>= 1) {
#pragma unroll
                    for (int j = 0; j < PL; ++j) {
                        ps[j] += __shfl_xor(ps[j], m, 64);
                        pd[j] += __shfl_xor(pd[j], m, 64);
                    }
                }
                if (ALPHA == 1) {
                    if ((lane & 31) == 0) {
                        int idx = n * 2 + (lane >> 5);
                        alpS[idx] = ps[0]; alpD[idx] = pd[0];
                    }
                } else if (ALPHA == 2) {
                    if (lane == 0) {
#pragma unroll
                        for (int j = 0; j < PL; ++j) {
                            alpS[n * 2 + j] = ps[j]; alpD[n * 2 + j] = pd[j];
                        }
                    }
                } else {
                    if (lane == 0) { alpS[n] = ps[0]; alpD[n] = pd[0]; }
                }
            }
        }
    }
}

// ---------------------------------------------------------------------------
// Aggregate R10: one wave per dst node, 64-edge chunks.
//   Phase A (lane = edge): coalesced csr_src, float2 alpha_s, leaky, wave
//     butterfly max -> chunk-level rescale of (m,den,acc), lane-parallel
//     p=exp(lg-m), butterfly den sum. 1 exp per 64 edges (per head).
//   Phase B (broadcast): (src,p) staged in per-wave LDS slice (wave-sync,
//     no barrier needed); per edge: uniform LDS read + readfirstlane scalar
//     base + PL loads + PL FMA.
// Template: (H,C,PL) in {(2,32,1), (2,64,2), (1,64,1)}; M=H*C.
// ---------------------------------------------------------------------------
template <int H, int C, int PL>
__global__ __launch_bounds__(256) void aggregate_kernel(
        const float* __restrict__ h,
        const float* __restrict__ alpha_s,
        const float* __restrict__ alpha_d,
        const int* __restrict__ row_ptr,
        const int* __restrict__ csr_src,
        const float* __restrict__ bias,
        float* __restrict__ out, int N) {
    constexpr int M = H * C;
    __shared__ int   ss[4][64];
    __shared__ float sp[4][128];
    const int wid  = threadIdx.x >> 6;
    const int lane = threadIdx.x & 63;
    const int n = blockIdx.x * 4 + wid;
    if (n >= N) return;

    const int lo = row_ptr[n], hi = row_ptr[n + 1];
    const int myhead = (PL == 1 && H == 2) ? (lane / C) : 0;

    float adv[H];
#pragma unroll
    for (int t = 0; t < H; ++t) adv[t] = alpha_d[n * H + t];

    float m[H], den[H], acc[PL];
#pragma unroll
    for (int t = 0; t < H; ++t) { m[t] = -INFINITY; den[t] = 0.0f; }
#pragma unroll
    for (int j = 0; j < PL; ++j) acc[j] = 0.0f;

    for (int e0 = lo; e0 < hi; e0 += 64) {
        const int idx = e0 + lane;
        const bool valid = idx < hi;
        const int src_l = csr_src[valid ? idx : hi - 1];

        // ---- phase A: lane-parallel logits ----
        float lg[H];
        if (H == 2) {
            float2 as = ((const float2*)alpha_s)[src_l];
            lg[0] = as.x + adv[0];
            lg[1] = as.y + adv[1];
        } else {
            lg[0] = alpha_s[src_l] + adv[0];
        }
#pragma unroll
        for (int t = 0; t < H; ++t) {
            float v = lg[t];
            v = v > 0.0f ? v : 0.2f * v;
            lg[t] = valid ? v : -INFINITY;
        }
        // chunk max (butterfly, result uniform)
        float cm[H];
#pragma unroll
        for (int t = 0; t < H; ++t) cm[t] = lg[t];
        for (int mm = 32; mm >= 1; mm >>= 1) {
#pragma unroll
            for (int t = 0; t < H; ++t)
                cm[t] = fmaxf(cm[t], __shfl_xor(cm[t], mm, 64));
        }
        // chunk-level rescale (exp(0)=1 when max unchanged; exp(-inf)=0 first chunk)
        float sc[H];
#pragma unroll
        for (int t = 0; t < H; ++t) {
            float mnew = fmaxf(m[t], cm[t]);
            sc[t] = __expf(m[t] - mnew);
            den[t] *= sc[t];
            m[t] = mnew;
        }
        if (PL == 2) {
#pragma unroll
            for (int j = 0; j < PL; ++j) acc[j] *= sc[j];
        } else {
            float smine = (H == 1) ? sc[0] : (myhead == 0 ? sc[0] : sc[1]);
            acc[0] *= smine;
        }
        // lane-parallel p and den sum
        float p[H], dsum[H];
#pragma unroll
        for (int t = 0; t < H; ++t) { p[t] = __expf(lg[t] - m[t]); dsum[t] = p[t]; }
        for (int mm = 32; mm >= 1; mm >>= 1) {
#pragma unroll
            for (int t = 0; t < H; ++t)
                dsum[t] += __shfl_xor(dsum[t], mm, 64);
        }
#pragma unroll
        for (int t = 0; t < H; ++t) den[t] += dsum[t];

        // stage (src, p) in this wave's LDS slice (wave-synchronous)
        ss[wid][lane] = src_l;
        if (H == 2) ((float2*)sp[wid])[lane] = make_float2(p[0], p[1]);
        else        sp[wid][lane] = p[0];

        // ---- phase B: per-edge broadcast accumulate ----
        int nu = hi - e0; if (nu > 64) nu = 64;
        int u = 0;
#pragma unroll 1
        for (; u + 4 <= nu; u += 4) {
            int su0 = __builtin_amdgcn_readfirstlane(ss[wid][u + 0]);
            int su1 = __builtin_amdgcn_readfirstlane(ss[wid][u + 1]);
            int su2 = __builtin_amdgcn_readfirstlane(ss[wid][u + 2]);
            int su3 = __builtin_amdgcn_readfirstlane(ss[wid][u + 3]);
            const float* hp0 = h + (size_t)su0 * M;
            const float* hp1 = h + (size_t)su1 * M;
            const float* hp2 = h + (size_t)su2 * M;
            const float* hp3 = h + (size_t)su3 * M;
            if (H == 2) {
                const float2* pb = (const float2*)sp[wid];
                float2 q0 = pb[u + 0], q1 = pb[u + 1], q2 = pb[u + 2], q3 = pb[u + 3];
                if (PL == 2) {
                    float a0 = hp0[lane], b0 = hp0[lane + C];
                    float a1 = hp1[lane], b1 = hp1[lane + C];
                    float a2 = hp2[lane], b2 = hp2[lane + C];
                    float a3 = hp3[lane], b3 = hp3[lane + C];
                    acc[0] += q0.x * a0; acc[PL - 1] += q0.y * b0;
                    acc[0] += q1.x * a1; acc[PL - 1] += q1.y * b1;
                    acc[0] += q2.x * a2; acc[PL - 1] += q2.y * b2;
                    acc[0] += q3.x * a3; acc[PL - 1] += q3.y * b3;
                } else {
                    float a0 = hp0[lane], a1 = hp1[lane], a2 = hp2[lane], a3 = hp3[lane];
                    float p0 = myhead == 0 ? q0.x : q0.y;
                    float p1 = myhead == 0 ? q1.x : q1.y;
                    float p2 = myhead == 0 ? q2.x : q2.y;
                    float p3 = myhead == 0 ? q3.x : q3.y;
                    acc[0] += p0 * a0; acc[0] += p1 * a1;
                    acc[0] += p2 * a2; acc[0] += p3 * a3;
                }
            } else {
                float q0 = sp[wid][u + 0], q1 = sp[wid][u + 1];
                float q2 = sp[wid][u + 2], q3 = sp[wid][u + 3];
                float a0 = hp0[lane], a1 = hp1[lane], a2 = hp2[lane], a3 = hp3[lane];
                acc[0] += q0 * a0; acc[0] += q1 * a1;
                acc[0] += q2 * a2; acc[0] += q3 * a3;
            }
        }
#pragma unroll 1
        for (; u < nu; ++u) {
            int su = __builtin_amdgcn_readfirstlane(ss[wid][u]);
            const float* hp = h + (size_t)su * M;
            if (H == 2) {
                float2 q = ((const float2*)sp[wid])[u];
                if (PL == 2) {
                    acc[0] += q.x * hp[lane];
                    acc[PL - 1] += q.y * hp[lane + C];
                } else {
                    float pv = myhead == 0 ? q.x : q.y;
                    acc[0] += pv * hp[lane];
                }
            } else {
                acc[0] += sp[wid][u] * hp[lane];
            }
        }
    }

    if (PL == 2) {
#pragma unroll
        for (int j = 0; j < PL; ++j) {
            float v = acc[j] / den[j] + bias[j * C + lane];
            out[(size_t)n * M + j * C + lane] = fmaxf(v, 0.0f);
        }
    } else {
        float dv = (H == 1) ? den[0] : (myhead == 0 ? den[0] : den[1]);
        float v = acc[0] / dv + bias[lane];
        out[(size_t)n * M + lane] = fmaxf(v, 0.0f);
    }
}

// ---------------------------------------------------------------------------

extern "C" void kernel_launch(void* const* d_in, const int* in_sizes, int n_in,
                              void* d_out, int out_size, void* d_ws, size_t ws_size,
                              hipStream_t stream) {
    const float* x   = (const float*)d_in[0];
    const int*   ei  = (const int*)  d_in[1];
    const float* w1  = (const float*)d_in[2];
    const float* as1 = (const float*)d_in[3];
    const float* ad1 = (const float*)d_in[4];
    const float* b1  = (const float*)d_in[5];
    const float* w2  = (const float*)d_in[6];
    const float* as2 = (const float*)d_in[7];
    const float* ad2 = (const float*)d_in[8];
    const float* b2  = (const float*)d_in[9];
    const float* w3  = (const float*)d_in[10];
    const float* as3 = (const float*)d_in[11];
    const float* ad3 = (const float*)d_in[12];
    const float* b3  = (const float*)d_in[13];
    const float* fcw = (const float*)d_in[14];
    const float* fcb = (const float*)d_in[15];
    float* out = (float*)d_out;

    const int N = in_sizes[0] / 128;
    const int E = in_sizes[1] / 2;
    const int Etot = E + N;

    // workspace carve-up (256B aligned regions)
    char* p = (char*)d_ws;
    auto alloc = [&](size_t bytes) {
        char* r = p;
        p += (bytes + 255) & ~(size_t)255;
        return r;
    };
    int*   cnt     = (int*)  alloc((size_t)N * 4);
    int*   row_ptr = (int*)  alloc((size_t)(N + 1) * 4);
    int*   rank    = (int*)  alloc((size_t)Etot * 4);
    int*   csr_src = (int*)  alloc((size_t)Etot * 4);
    float* bufA    = (float*)alloc((size_t)N * 128 * 4);
    float* bufB    = (float*)alloc((size_t)N * 128 * 4);
    float* alpS    = (float*)alloc((size_t)N * 2 * 4);
    float* alpD    = (float*)alloc((size_t)N * 2 * 4);
    (void)ws_size; (void)n_in; (void)out_size;

    // ---- build CSR by dst (atomics only in pass 1) ----
    hipMemsetAsync(cnt, 0, (size_t)N * 4, stream);
    int eb4 = (Etot / 4 + 255) / 256 + 1;   // 4 edges/thread
    count_rank_kernel<<<eb4, 256, 0, stream>>>(ei, E, N, cnt, rank);
    scan_kernel<<<1, 1024, 0, stream>>>(cnt, N, Etot, row_ptr);
    scatter_kernel<<<eb4, 256, 0, stream>>>(ei, E, N, row_ptr, rank, csr_src);

    int gb = (N + 3) / 4;         // aggregate: 4 waves/block, 1 node/wave
    const int GB = 1024;          // gemm persistent blocks: 4/CU (VGPR/LDS cap at RB=8)

    // ---- layer 1: 128 -> H2 x C32, concat ----
    gemm_kernel<128, 64, 8, 1><<<dim3(GB, 1), 256, 0, stream>>>(
        x, w1, nullptr, bufA, as1, ad1, alpS, alpD, N, 64, 0);
    aggregate_kernel<2, 32, 1><<<gb, 256, 0, stream>>>(bufA, alpS, alpD, row_ptr, csr_src, b1, bufB, N);

    // ---- layer 2: 64 -> H2 x C64, concat ----
    gemm_kernel<64, 128, 8, 2><<<dim3(GB, 1), 256, 0, stream>>>(
        bufB, w2, nullptr, bufA, as2, ad2, alpS, alpD, N, 128, 0);
    aggregate_kernel<2, 64, 2><<<gb, 256, 0, stream>>>(bufA, alpS, alpD, row_ptr, csr_src, b2, bufB, N);

    // ---- layer 3: 128 -> H1 x C64, mean (=identity for 1 head) ----
    gemm_kernel<128, 64, 8, 3><<<dim3(GB, 1), 256, 0, stream>>>(
        bufB, w3, nullptr, bufA, as3, ad3, alpS, alpD, N, 64, 0);
    aggregate_kernel<1, 64, 1><<<gb, 256, 0, stream>>>(bufA, alpS, alpD, row_ptr, csr_src, b3, bufB, N);

    // ---- FC: 64 -> 512 + relu ----
    gemm_kernel<64, 128, 8, 0><<<dim3(GB / 4, 4), 256, 0, stream>>>(
        bufB, fcw, fcb, out, nullptr, nullptr, nullptr, nullptr, N, 512, 1);
}